// Round 13
// baseline (438.533 us; speedup 1.0000x reference)
//
#include <hip/hip_runtime.h>
#include <hip/hip_bf16.h>
#include <hip/hip_fp16.h>

// Problem constants (match reference)
#define NN     20000
#define ERAW   320000
#define ETOT   (ERAW + NN)   // 340000 with self loops
#define F_IN   50
#define HID    64
#define HEADS  8
#define WIDTH  512           // HID*HEADS
#define NCLS   121
#define NCLS_P 128           // padded cols for layer-3 MFMA GEMM + h16 stride

typedef __attribute__((ext_vector_type(8))) __bf16 bf16x8;
typedef __attribute__((ext_vector_type(4))) float floatx4;

// ---------------- fp32 -> bf16 split helpers --------------------------------
__device__ __forceinline__ unsigned short f32_to_bf16_rn(float f) {
  unsigned u = __float_as_uint(f);
  unsigned r = u + 0x7fffu + ((u >> 16) & 1u);
  return (unsigned short)(r >> 16);
}
__device__ __forceinline__ void split_one(float f, unsigned short& h,
                                          unsigned short& l) {
  h = f32_to_bf16_rn(f);
  float fh = __uint_as_float(((unsigned)h) << 16);
  l = f32_to_bf16_rn(f - fh);
}

__device__ __forceinline__ float2 u2f2(unsigned u) {
  __half2 hv = *reinterpret_cast<__half2*>(&u);
  return __half22float2(hv);
}

// async global -> LDS, 16B per lane (dest = wave-uniform base + lane*16)
__device__ __forceinline__ void gll16(const unsigned short* g,
                                      const unsigned short* l) {
  __builtin_amdgcn_global_load_lds(
      (const __attribute__((address_space(1))) unsigned int*)(const void*)g,
      (__attribute__((address_space(3))) unsigned int*)(void*)l, 16, 0, 0);
}

// ---- ONE weight-prep kernel (replaces 4 dispatches) ------------------------
#define PW_BLOCKS 449
__global__ __launch_bounds__(256) void prep_weights(
    const float* __restrict__ W1, const float* __restrict__ W2,
    const float* __restrict__ W3, const float* __restrict__ a1s,
    const float* __restrict__ a1d, unsigned short* __restrict__ w1hHi,
    unsigned short* __restrict__ w1hLo, unsigned short* __restrict__ w2tHi,
    unsigned short* __restrict__ w2tLo, unsigned short* __restrict__ w3tHi,
    unsigned short* __restrict__ w3tLo, float* __restrict__ w1as,
    float* __restrict__ w1ad) {
  __shared__ float t[32][33];
  const int b = blockIdx.x;
  if (b < 320) {
    const float* W;
    unsigned short *thi, *tlo;
    int M, Mp, bx, by;
    const int K = WIDTH;
    if (b < 256) {
      W = W2; thi = w2tHi; tlo = w2tLo; M = WIDTH; Mp = WIDTH;
      bx = b & 15; by = b >> 4;
    } else {
      int bb = b - 256;
      W = W3; thi = w3tHi; tlo = w3tLo; M = NCLS; Mp = NCLS_P;
      bx = bb & 15; by = bb >> 4;
    }
    int k0 = bx * 32, m0 = by * 32;
    int tx = threadIdx.x & 31, ty = threadIdx.x >> 5;  // 32 x 8
    #pragma unroll
    for (int r = 0; r < 4; ++r) {
      int k = k0 + ty + r * 8, m = m0 + tx;
      float v = 0.f;
      if (k < K && m < M) v = W[(size_t)k * M + m];
      t[ty + r * 8][tx] = v;
    }
    __syncthreads();
    #pragma unroll
    for (int r = 0; r < 4; ++r) {
      int m = m0 + ty + r * 8, k = k0 + tx;
      if (m < Mp && k < K) {
        unsigned short h, l;
        split_one(t[tx][ty + r * 8], h, l);
        thi[(size_t)m * K + k] = h;
        tlo[(size_t)m * K + k] = l;
      }
    }
  } else if (b < 448) {
    int idx = (b - 320) * 256 + threadIdx.x;
    if (idx < HEADS * HID * HID) {
      int hd = idx >> 12, rem = idx & 4095;
      int col = rem >> 6, k = rem & 63;
      float v = (k < F_IN) ? W1[(size_t)k * WIDTH + hd * HID + col] : 0.f;
      unsigned short h, l;
      split_one(v, h, l);
      w1hHi[idx] = h;
      w1hLo[idx] = l;
    }
  } else {
    for (int idx = threadIdx.x; idx < 2 * F_IN * HEADS; idx += 256) {
      int which = idx >= F_IN * HEADS;
      int r = which ? idx - F_IN * HEADS : idx;
      int k = r >> 3, h = r & 7;
      const float* a = which ? a1d : a1s;
      float s = 0.f;
      for (int c = 0; c < HID; ++c)
        s += W1[(size_t)k * WIDTH + h * HID + c] * a[h * HID + c];
      (which ? w1ad : w1as)[r] = s;
    }
  }
}

// ---- split-bf16 MFMA GEMM, (MI*32)x128 tile, BK=64, 8 waves ---------------
// R13: stage ONLY the hi-streams in LDS (Ahi+Bhi, 32KB/buffer at MI=4);
// Alo/Blo fragments are loaded global->register at the use site. A-panel lo
// rows are L2-hot (all col-blocks of a row-panel on one XCD via swizzle);
// B is 2MB L2-resident. LDS 128KB->64KB => 2 blocks/CU = 4 waves/SIMD
// (was 1 block / 2 waves -- the R8-R12 occupancy cap). Fragment VALUES and
// MFMA order unchanged -> bit-identical. __launch_bounds__(512,4) caps VGPR
// at 128 so the 2-block occupancy is realized.
// Staging/swizzle otherwise as R10: 128B LDS rows, chunk c at slot c^(r&7)
// via pre-swizzled global source (linear dest, rule #21); counted vmcnt.
template <int MI>
__global__ __launch_bounds__(512, 4) void gemm_split_db(
    const unsigned short* __restrict__ Ahi, const unsigned short* __restrict__ Alo,
    const unsigned short* __restrict__ Bthi, const unsigned short* __restrict__ Btlo,
    __half* __restrict__ C16, int N, int K, int M, int Mp, int RB, int CB) {
  constexpr int ABUF = MI * 2048;          // ushorts of Ahi region (rows*64)
  constexpr int BUF = MI * 2048 + 8192;    // ushorts per buffer (Ahi+Bhi)
  constexpr int NGW = (MI * 4 + 16) / 8;   // gll16 per wave per K-step
  __shared__ unsigned short lds[2 * BUF];

  const int f = blockIdx.x;
  const int xcd = f & 7;
  const int g = f >> 3;
  const int cb = g % CB;
  const int rb = (g / CB) * 8 + xcd;
  if (rb >= RB) return;
  const int r0 = rb * (MI * 32), c0 = cb * 128;

  const int tid = threadIdx.x;
  const int wave = tid >> 6, lane = tid & 63;
  const int wr = wave >> 2, wc = wave & 3;  // 2x4 waves, (MI*16)x32 out each
  const int lkg = lane >> 4, lmn = lane & 15;

  const int row8 = lane >> 3, cslot = lane & 7;
  const unsigned short* gsrc[NGW];
  int ldsoff[NGW];
  #pragma unroll
  for (int i = 0; i < NGW; ++i) {
    int q = wave * NGW + i;
    int a = (q < MI * 4) ? 0 : 1;          // 0 = Ahi, 1 = Bhi
    int rg = (a == 0) ? q : q - MI * 4;
    int r = rg * 8 + row8;
    int c = cslot ^ (r & 7);              // pre-swizzled chunk (involution)
    const unsigned short* base = a ? Bthi : Ahi;
    size_t grow;
    if (a == 0) {
      int ra = r0 + r;
      if (ra > N - 1) ra = N - 1;
      grow = (size_t)ra;
    } else {
      grow = (size_t)(c0 + r);
    }
    gsrc[i] = base + grow * K + c * 8;
    ldsoff[i] = (a ? ABUF : 0) + rg * 512;  // wave-uniform dest base
  }

  // hi ds_read bases + lo global pointers (per fragment, loop-invariant)
  int rowA[MI], m7A[MI], rowB[2], m7B[2];
  const unsigned short* loA[MI];
  const unsigned short* loB[2];
  #pragma unroll
  for (int mi = 0; mi < MI; ++mi) {
    int m = wr * (MI * 16) + mi * 16 + lmn;
    rowA[mi] = m * 64;  m7A[mi] = m & 7;
    int ra = r0 + m; if (ra > N - 1) ra = N - 1;
    loA[mi] = Alo + (size_t)ra * K + lkg * 8;
  }
  #pragma unroll
  for (int ni = 0; ni < 2; ++ni) {
    int n = wc * 32 + ni * 16 + lmn;
    rowB[ni] = ABUF + n * 64;  m7B[ni] = n & 7;
    loB[ni] = Btlo + (size_t)(c0 + n) * K + lkg * 8;
  }

  floatx4 acc[MI][2] = {};

  // prologue: tile 0 hi -> buffer 0
  #pragma unroll
  for (int i = 0; i < NGW; ++i) gll16(gsrc[i], lds + ldsoff[i]);

  const int nk = K >> 6;  // K-steps of 64
  for (int t = 0; t < nk; ++t) {
    if (t + 1 < nk) {
      const unsigned short* dst = lds + ((t + 1) & 1) * BUF;
      #pragma unroll
      for (int i = 0; i < NGW; ++i)
        gll16(gsrc[i] + (t + 1) * 64, dst + ldsoff[i]);
      if constexpr (MI == 4) {
        asm volatile("s_waitcnt vmcnt(4)" ::: "memory");  // tile t landed
      } else {
        asm volatile("s_waitcnt vmcnt(3)" ::: "memory");
      }
    } else {
      asm volatile("s_waitcnt vmcnt(0)" ::: "memory");
    }
    __builtin_amdgcn_sched_barrier(0);
    __builtin_amdgcn_s_barrier();          // all waves' tile-t loads visible
    __builtin_amdgcn_sched_barrier(0);

    const unsigned short* Lb = lds + (t & 1) * BUF;
    const int kofs = t * 64;
    #pragma unroll
    for (int ksub = 0; ksub < 2; ++ksub) {  // ascending K within tile
      bf16x8 fAhi[MI], fAlo[MI], fBhi[2], fBlo[2];
      #pragma unroll
      for (int mi = 0; mi < MI; ++mi) {
        int s = rowA[mi] + (((ksub << 2) | lkg) ^ m7A[mi]) * 8;
        fAhi[mi] = *(const bf16x8*)(Lb + s);
        fAlo[mi] = *(const bf16x8*)(loA[mi] + kofs + ksub * 32);  // L2-hot
      }
      #pragma unroll
      for (int ni = 0; ni < 2; ++ni) {
        int s = rowB[ni] + (((ksub << 2) | lkg) ^ m7B[ni]) * 8;
        fBhi[ni] = *(const bf16x8*)(Lb + s);
        fBlo[ni] = *(const bf16x8*)(loB[ni] + kofs + ksub * 32);  // L2-hot
      }
      // same 3-term split, same per-acc order as before -> bit-identical
      #pragma unroll
      for (int mi = 0; mi < MI; ++mi)
        #pragma unroll
        for (int ni = 0; ni < 2; ++ni) {
          acc[mi][ni] = __builtin_amdgcn_mfma_f32_16x16x32_bf16(
              fAhi[mi], fBhi[ni], acc[mi][ni], 0, 0, 0);
          acc[mi][ni] = __builtin_amdgcn_mfma_f32_16x16x32_bf16(
              fAhi[mi], fBlo[ni], acc[mi][ni], 0, 0, 0);
          acc[mi][ni] = __builtin_amdgcn_mfma_f32_16x16x32_bf16(
              fAlo[mi], fBhi[ni], acc[mi][ni], 0, 0, 0);
        }
    }

    __builtin_amdgcn_sched_barrier(0);
    asm volatile("s_waitcnt lgkmcnt(0)" ::: "memory");
    __builtin_amdgcn_s_barrier();          // WAR: next issue overwrites buf
    __builtin_amdgcn_sched_barrier(0);
  }

  #pragma unroll
  for (int mi = 0; mi < MI; ++mi) {
    #pragma unroll
    for (int r = 0; r < 4; ++r) {
      int grow = r0 + wr * (MI * 16) + mi * 16 + lkg * 4 + r;
      if (grow >= N) continue;
      #pragma unroll
      for (int ni = 0; ni < 2; ++ni) {
        int gcol = c0 + wc * 32 + ni * 16 + lmn;
        float v = (gcol < M) ? acc[mi][ni][r] : 0.f;
        C16[(size_t)grow * Mp + gcol] = __float2half(v);
      }
    }
  }
}

// ---- batched per-head L1 GEMM: C[n,hd*64+c] = elu(A[n,hd*64+:64]@W1h + b1) -
__global__ __launch_bounds__(256) void gemm_l1_heads(
    const unsigned short* __restrict__ Ahi, const unsigned short* __restrict__ Alo,
    const unsigned short* __restrict__ Bthi, const unsigned short* __restrict__ Btlo,
    unsigned short* __restrict__ outHi, unsigned short* __restrict__ outLo,
    const float* __restrict__ bias) {
  __shared__ unsigned short sAhi[8192], sAlo[8192], sBhi[4096], sBlo[4096];
  const int tid = threadIdx.x;
  const int wave = tid >> 6, lane = tid & 63;
  const int r0 = blockIdx.x * 128;
  const int hd = blockIdx.y;
  const int lkg = lane >> 4, lmn = lane & 15;

  #pragma unroll
  for (int t = 0; t < 4; ++t) {
    int cid = tid + t * 256;
    int row = cid >> 3, c = cid & 7;
    int gr = r0 + row; if (gr > NN - 1) gr = NN - 1;
    const size_t goff = (size_t)gr * WIDTH + hd * HID + c * 8;
    int loff = (((c >> 2) * 4 + (c & 3)) * 128 + row) * 8;
    *(uint4*)(sAhi + loff) = *(const uint4*)(Ahi + goff);
    *(uint4*)(sAlo + loff) = *(const uint4*)(Alo + goff);
  }
  #pragma unroll
  for (int t = 0; t < 2; ++t) {
    int cid = tid + t * 256;
    int col = cid >> 3, c = cid & 7;
    const size_t goff = (size_t)(hd * HID + col) * HID + c * 8;
    int loff = (((c >> 2) * 4 + (c & 3)) * 64 + col) * 8;
    *(uint4*)(sBhi + loff) = *(const uint4*)(Bthi + goff);
    *(uint4*)(sBlo + loff) = *(const uint4*)(Btlo + goff);
  }
  __syncthreads();

  floatx4 acc[2][4] = {};
  #pragma unroll
  for (int ks = 0; ks < 2; ++ks) {
    bf16x8 fAhi[2], fAlo[2], fBhi[4], fBlo[4];
    #pragma unroll
    for (int mi = 0; mi < 2; ++mi) {
      int m = wave * 32 + mi * 16 + lmn;
      int off = ((ks * 4 + lkg) * 128 + m) * 8;
      fAhi[mi] = *(const bf16x8*)(sAhi + off);
      fAlo[mi] = *(const bf16x8*)(sAlo + off);
    }
    #pragma unroll
    for (int ni = 0; ni < 4; ++ni) {
      int n = ni * 16 + lmn;
      int off = ((ks * 4 + lkg) * 64 + n) * 8;
      fBhi[ni] = *(const bf16x8*)(sBhi + off);
      fBlo[ni] = *(const bf16x8*)(sBlo + off);
    }
    #pragma unroll
    for (int mi = 0; mi < 2; ++mi)
      #pragma unroll
      for (int ni = 0; ni < 4; ++ni) {
        acc[mi][ni] = __builtin_amdgcn_mfma_f32_16x16x32_bf16(
            fAhi[mi], fBhi[ni], acc[mi][ni], 0, 0, 0);
        acc[mi][ni] = __builtin_amdgcn_mfma_f32_16x16x32_bf16(
            fAhi[mi], fBlo[ni], acc[mi][ni], 0, 0, 0);
        acc[mi][ni] = __builtin_amdgcn_mfma_f32_16x16x32_bf16(
            fAlo[mi], fBhi[ni], acc[mi][ni], 0, 0, 0);
      }
  }

  #pragma unroll
  for (int mi = 0; mi < 2; ++mi) {
    #pragma unroll
    for (int r = 0; r < 4; ++r) {
      int grow = r0 + wave * 32 + mi * 16 + (lane >> 4) * 4 + r;
      if (grow >= NN) continue;
      #pragma unroll
      for (int ni = 0; ni < 4; ++ni) {
        int gcol = hd * HID + ni * 16 + lmn;
        float v = acc[mi][ni][r] + bias[gcol];
        v = (v > 0.f) ? v : (__expf(v) - 1.0f);
        unsigned short hh, ll;
        split_one(v, hh, ll);
        outHi[(size_t)grow * WIDTH + gcol] = hh;
        outLo[(size_t)grow * WIDTH + gcol] = ll;
      }
    }
  }
}

// al1[n,h] = sum_k x[n,k] * w1a[k,h]   (one wave per node)
__global__ __launch_bounds__(256) void al1_kernel(
    const float* __restrict__ x, const float* __restrict__ w1as,
    const float* __restrict__ w1ad, float* __restrict__ al_s,
    float* __restrict__ al_d) {
  int n = (blockIdx.x * blockDim.x + threadIdx.x) >> 6;
  int lane = threadIdx.x & 63;
  if (n >= NN) return;
  float xv = (lane < F_IN) ? x[(size_t)n * F_IN + lane] : 0.f;
  float ws[HEADS], wd[HEADS];
  #pragma unroll
  for (int h = 0; h < HEADS; ++h) {
    ws[h] = (lane < F_IN) ? w1as[lane * HEADS + h] : 0.f;
    wd[h] = (lane < F_IN) ? w1ad[lane * HEADS + h] : 0.f;
  }
  #pragma unroll
  for (int h = 0; h < HEADS; ++h) {
    float ss = xv * ws[h], sd = xv * wd[h];
    #pragma unroll
    for (int o = 32; o; o >>= 1) {
      ss += __shfl_xor(ss, o);
      sd += __shfl_xor(sd, o);
    }
    if (lane == 0) {
      al_s[n * HEADS + h] = ss;
      al_d[n * HEADS + h] = sd;
    }
  }
}

// ---------------- per-node attention logits from fp16 h (H=1 layers) -------
template <int C, int CS>
__global__ __launch_bounds__(256) void compute_al16(
    const __half* __restrict__ h16, const float* __restrict__ a_src,
    const float* __restrict__ a_dst, float* __restrict__ al_s,
    float* __restrict__ al_d) {
  int n = (blockIdx.x * blockDim.x + threadIdx.x) >> 6;
  int lane = threadIdx.x & 63;
  if (n >= NN) return;
  const __half* hr = h16 + (size_t)n * CS;
  float ss = 0.f, sd = 0.f;
  if (C % 512 == 0) {
    uint4 raw = *(const uint4*)(hr + lane * 8);
    float f[8];
    float2 t;
    t = u2f2(raw.x); f[0] = t.x; f[1] = t.y;
    t = u2f2(raw.y); f[2] = t.x; f[3] = t.y;
    t = u2f2(raw.z); f[4] = t.x; f[5] = t.y;
    t = u2f2(raw.w); f[6] = t.x; f[7] = t.y;
    #pragma unroll
    for (int j = 0; j < 8; ++j) {
      int c = lane * 8 + j;
      ss += f[j] * a_src[c];
      sd += f[j] * a_dst[c];
    }
  } else {
    for (int c = lane; c < C; c += 64) {
      float v = __half2float(hr[c]);
      ss += v * a_src[c];
      sd += v * a_dst[c];
    }
  }
  #pragma unroll
  for (int o = 32; o; o >>= 1) {
    ss += __shfl_xor(ss, o);
    sd += __shfl_xor(sd, o);
  }
  if (lane == 0) {
    al_s[n] = ss;
    al_d[n] = sd;
  }
}

// ---------------- CSR build (once; shared by all layers) --------------------
__global__ __launch_bounds__(256) void count_deg(
    const int* __restrict__ edst, int* __restrict__ deg) {
  int e = blockIdx.x * blockDim.x + threadIdx.x;
  if (e >= ETOT) return;
  int d = (e < ERAW) ? edst[e] : (e - ERAW);
  atomicAdd(&deg[d], 1);
}

__global__ __launch_bounds__(1024) void scan_deg(
    const int* __restrict__ deg, int* __restrict__ rowptr) {
  __shared__ int part[1024];
  const int t = threadIdx.x;
  const int CHUNK = (NN + 1023) / 1024;
  int lo = t * CHUNK, hi = min(lo + CHUNK, NN);
  int s = 0;
  for (int i = lo; i < hi; ++i) s += deg[i];
  part[t] = s;
  __syncthreads();
  for (int off = 1; off < 1024; off <<= 1) {
    int v = (t >= off) ? part[t - off] : 0;
    __syncthreads();
    part[t] += v;
    __syncthreads();
  }
  int base = (t == 0) ? 0 : part[t - 1];
  for (int i = lo; i < hi; ++i) {
    rowptr[i] = base;
    base += deg[i];
  }
  if (t == 1023) rowptr[NN] = part[1023];
}

__global__ __launch_bounds__(256) void scatter_csr(
    const int* __restrict__ esrc, const int* __restrict__ edst,
    const int* __restrict__ rowptr, int* __restrict__ cnt,
    int* __restrict__ csrc) {
  int e = blockIdx.x * blockDim.x + threadIdx.x;
  if (e >= ETOT) return;
  int s, d;
  if (e < ERAW) { s = esrc[e]; d = edst[e]; }
  else          { s = e - ERAW; d = e - ERAW; }
  int pos = rowptr[d] + atomicAdd(&cnt[d], 1);
  csrc[pos] = s;
}

// ---- layer-1 fused SINGLE-PASS softmax+aggregate (self-loop-logit shift) --
// (R10 form: unroll-8 chunks + scalar tail; ascending-p order)
__global__ __launch_bounds__(256) void agg_x_sm(
    const int* __restrict__ rowptr, const int* __restrict__ csrc,
    const float* __restrict__ al_s, const float* __restrict__ al_d,
    const float* __restrict__ x, unsigned short* __restrict__ outHi,
    unsigned short* __restrict__ outLo) {
  const int w = threadIdx.x >> 6, lane = threadIdx.x & 63;
  const int d = blockIdx.x * 4 + w;
  if (d >= NN) return;
  const int r0 = rowptr[d], r1 = rowptr[d + 1];
  const int mh = lane & 7;
  const float ald_my = al_d[d * HEADS + mh];
  float m_my = al_s[d * HEADS + mh] + ald_my;
  m_my = (m_my > 0.f) ? m_my : 0.2f * m_my;

  float z_my = 0.f;
  float acc[HEADS];
  #pragma unroll
  for (int hh = 0; hh < HEADS; ++hh) acc[hh] = 0.f;

  int p = r0;
  for (; p + 8 <= r1; p += 8) {
    int s[8];
    #pragma unroll
    for (int j = 0; j < 8; ++j) s[j] = csrc[p + j];
    float xv[8];
    #pragma unroll
    for (int j = 0; j < 8; ++j)
      xv[j] = (lane < F_IN) ? x[(size_t)s[j] * F_IN + lane] : 0.f;
    float av[8];
    #pragma unroll
    for (int j = 0; j < 8; ++j) av[j] = al_s[s[j] * HEADS + mh];
    #pragma unroll
    for (int j = 0; j < 8; ++j) {          // strictly ascending p
      float v = av[j] + ald_my;
      v = (v > 0.f) ? v : 0.2f * v;
      float a = __expf(v - m_my);
      z_my += a;
      #pragma unroll
      for (int hh = 0; hh < HEADS; ++hh) acc[hh] += __shfl(a, hh, 8) * xv[j];
    }
  }
  for (; p < r1; ++p) {
    int s = csrc[p];
    float v = al_s[s * HEADS + mh] + ald_my;
    v = (v > 0.f) ? v : 0.2f * v;
    float a = __expf(v - m_my);
    z_my += a;
    float xv = (lane < F_IN) ? x[(size_t)s * F_IN + lane] : 0.f;
    #pragma unroll
    for (int hh = 0; hh < HEADS; ++hh) acc[hh] += __shfl(a, hh, 8) * xv;
  }

  #pragma unroll
  for (int hh = 0; hh < HEADS; ++hh) {
    float zh = __shfl(z_my, hh, 8);
    float v = (lane < F_IN) ? acc[hh] / (zh + 1e-16f) : 0.f;
    unsigned short h2, l2;
    split_one(v, h2, l2);
    outHi[(size_t)d * WIDTH + hh * HID + lane] = h2;
    outLo[(size_t)d * WIDTH + hh * HID + lane] = l2;
  }
}

// ---- L2 fused SINGLE-PASS softmax + pull aggregation (512 cols) -----------
// (R10 form: unroll-8 chunks + scalar tail, early gathers; bandwidth-bound)
__global__ __launch_bounds__(256) void pull_agg_w(
    const int* __restrict__ rowptr, const int* __restrict__ csrc,
    const float* __restrict__ al_s, const float* __restrict__ al_d,
    const __half* __restrict__ h16, const float* __restrict__ bias,
    unsigned short* __restrict__ outHi, unsigned short* __restrict__ outLo) {
  const int w = threadIdx.x >> 6;
  const int lane = threadIdx.x & 63;
  const int d = blockIdx.x * 4 + w;
  if (d >= NN) return;
  const int r0 = rowptr[d], r1 = rowptr[d + 1];
  const float ald = al_d[d];
  float m = al_s[d] + ald;                 // self-loop logit as softmax shift
  m = (m > 0.f) ? m : 0.2f * m;

  const int base = lane * 8;
  const __half* hb = h16 + base;
  float acc[8];
  #pragma unroll
  for (int j = 0; j < 8; ++j) acc[j] = 0.f;
  float z = 0.f;

  int p = r0;
  for (; p + 8 <= r1; p += 8) {
    int s[8];
    #pragma unroll
    for (int j = 0; j < 8; ++j) s[j] = csrc[p + j];
    uint4 raw8[8];
    #pragma unroll
    for (int j = 0; j < 8; ++j)
      raw8[j] = *(const uint4*)(hb + (size_t)s[j] * WIDTH);
    float av[8];
    #pragma unroll
    for (int j = 0; j < 8; ++j) av[j] = al_s[s[j]];
    #pragma unroll
    for (int j = 0; j < 8; ++j) {          // strictly ascending p
      float v = av[j] + ald;
      v = (v > 0.f) ? v : 0.2f * v;
      float a = __expf(v - m);
      z += a;
      float2 f0 = u2f2(raw8[j].x), f1 = u2f2(raw8[j].y);
      float2 f2 = u2f2(raw8[j].z), f3 = u2f2(raw8[j].w);
      acc[0] += f0.x * a; acc[1] += f0.y * a;
      acc[2] += f1.x * a; acc[3] += f1.y * a;
      acc[4] += f2.x * a; acc[5] += f2.y * a;
      acc[6] += f3.x * a; acc[7] += f3.y * a;
    }
  }
  for (; p < r1; ++p) {
    int s = csrc[p];
    float v = al_s[s] + ald;
    v = (v > 0.f) ? v : 0.2f * v;
    float a = __expf(v - m);
    z += a;
    uint4 raw = *(const uint4*)(hb + (size_t)s * WIDTH);
    float2 f0 = u2f2(raw.x), f1 = u2f2(raw.y);
    float2 f2 = u2f2(raw.z), f3 = u2f2(raw.w);
    acc[0] += f0.x * a; acc[1] += f0.y * a;
    acc[2] += f1.x * a; acc[3] += f1.y * a;
    acc[4] += f2.x * a; acc[5] += f2.y * a;
    acc[6] += f3.x * a; acc[7] += f3.y * a;
  }
  const float iz = 1.0f / (z + 1e-16f);

  #pragma unroll
  for (int j = 0; j < 8; ++j) {
    float v = acc[j] * iz + bias[base + j];
    v = (v > 0.f) ? v : (__expf(v) - 1.0f);   // ELU
    unsigned short hh, ll;
    split_one(v, hh, ll);
    outHi[(size_t)d * WIDTH + base + j] = hh;
    outLo[(size_t)d * WIDTH + base + j] = ll;
  }
}

// ---- L3 pull aggregation: TWO destinations per wave (half-wave each) ------
__global__ __launch_bounds__(256) void pull_agg_n(
    const int* __restrict__ rowptr, const int* __restrict__ csrc,
    const float* __restrict__ al_s, const float* __restrict__ al_d,
    const __half* __restrict__ h16, const float* __restrict__ bias,
    float* __restrict__ out) {
  const int w = threadIdx.x >> 6, lane = threadIdx.x & 63;
  const int half = lane >> 5, li = lane & 31;
  const int d = blockIdx.x * 8 + w * 2 + half;
  if (d >= NN) return;
  const int r0 = rowptr[d], r1 = rowptr[d + 1];
  const float ald = al_d[d];
  float m = al_s[d] + ald;
  m = (m > 0.f) ? m : 0.2f * m;

  const int base = li * 4;                // 32 lanes x 4 cols = 128
  const __half* hb = h16 + base;
  float acc[4] = {0.f, 0.f, 0.f, 0.f};
  float z = 0.f;

  for (int p = r0; p < r1; p += 8) {
    int s[8];
    #pragma unroll
    for (int j = 0; j < 8; ++j) {
      int pj = p + j; if (pj > r1 - 1) pj = r1 - 1;
      s[j] = csrc[pj];
    }
    uint2 raw[8];                          // 8B = 4 fp16
    #pragma unroll
    for (int j = 0; j < 8; ++j)
      raw[j] = *(const uint2*)(hb + (size_t)s[j] * NCLS_P);
    float av[8];
    #pragma unroll
    for (int j = 0; j < 8; ++j) av[j] = al_s[s[j]];
    #pragma unroll
    for (int j = 0; j < 8; ++j) {          // strictly ascending p
      float v = av[j] + ald;
      v = (v > 0.f) ? v : 0.2f * v;
      float a = __expf(v - m);
      if (p + j >= r1) a = 0.f;            // masked tail: exact +0.0f
      z += a;
      float2 f0 = u2f2(raw[j].x), f1 = u2f2(raw[j].y);
      acc[0] += f0.x * a; acc[1] += f0.y * a;
      acc[2] += f1.x * a; acc[3] += f1.y * a;
    }
  }
  const float iz = 1.0f / (z + 1e-16f);

  #pragma unroll
  for (int j = 0; j < 4; ++j) {
    int col = base + j;
    if (col < NCLS)
      out[(size_t)d * NCLS + col] = acc[j] * iz + bias[col];
  }
}

extern "C" void kernel_launch(void* const* d_in, const int* in_sizes, int n_in,
                              void* d_out, int out_size, void* d_ws,
                              size_t ws_size, hipStream_t stream) {
  const float* x      = (const float*)d_in[0];
  const int*   ei     = (const int*)d_in[1];
  const float* W1     = (const float*)d_in[2];
  const float* a1_src = (const float*)d_in[3];
  const float* a1_dst = (const float*)d_in[4];
  const float* b1     = (const float*)d_in[5];
  const float* W2     = (const float*)d_in[6];
  const float* a2_src = (const float*)d_in[7];
  const float* a2_dst = (const float*)d_in[8];
  const float* b2     = (const float*)d_in[9];
  const float* W3     = (const float*)d_in[10];
  const float* a3_src = (const float*)d_in[11];
  const float* a3_dst = (const float*)d_in[12];
  const float* b3     = (const float*)d_in[13];
  float* out = (float*)d_out;

  const int* esrc = ei;
  const int* edst = ei + ERAW;

  // Workspace carve-up
  unsigned short* p1Hi  = (unsigned short*)d_ws;          // NN*WIDTH
  unsigned short* p1Lo  = p1Hi + (size_t)NN * WIDTH;
  unsigned short* p2Hi  = p1Lo + (size_t)NN * WIDTH;
  unsigned short* p2Lo  = p2Hi + (size_t)NN * WIDTH;
  __half*        h16    = (__half*)(p2Lo + (size_t)NN * WIDTH);  // NN*WIDTH
  unsigned short* w1hHi = (unsigned short*)(h16 + (size_t)NN * WIDTH);
  unsigned short* w1hLo = w1hHi + (size_t)HEADS * HID * HID;
  unsigned short* w2tHi = w1hLo + (size_t)HEADS * HID * HID;  // 512*512
  unsigned short* w2tLo = w2tHi + (size_t)WIDTH * WIDTH;
  unsigned short* w3tHi = w2tLo + (size_t)WIDTH * WIDTH;  // 128*512
  unsigned short* w3tLo = w3tHi + (size_t)NCLS_P * WIDTH;
  float* al_s   = (float*)(w3tLo + (size_t)NCLS_P * WIDTH);  // NN*HEADS
  float* al_d   = al_s + (size_t)NN * HEADS;
  float* w1as   = al_d + (size_t)NN * HEADS;              // 50*8
  float* w1ad   = w1as + F_IN * HEADS;
  int* deg      = (int*)(w1ad + F_IN * HEADS);            // NN
  int* cnt      = deg + NN;                               // NN  (adjacent!)
  int* rowptr   = cnt + NN;                               // NN+1 (+3 pad)
  int* csrc     = rowptr + NN + 4;                        // ETOT

  // ---- build CSR by destination (once): ONE memset covers deg+cnt ----
  hipMemsetAsync(deg, 0, (size_t)(2 * NN) * sizeof(int), stream);
  const int eblk = (ETOT + 255) / 256;
  count_deg<<<eblk, 256, 0, stream>>>(edst, deg);
  scan_deg<<<1, 1024, 0, stream>>>(deg, rowptr);
  scatter_csr<<<eblk, 256, 0, stream>>>(esrc, edst, rowptr, cnt, csrc);

  // ---- ALL weight prep in one dispatch ----
  prep_weights<<<PW_BLOCKS, 256, 0, stream>>>(
      W1, W2, W3, a1_src, a1_dst, w1hHi, w1hLo, w2tHi, w2tLo, w3tHi, w3tLo,
      w1as, w1ad);

  const int nwblk = (NN + 3) / 4;

  // ---- Layer 1 (aggregate-x-first; single-pass softmax+agg; head GEMM) ----
  al1_kernel<<<nwblk, 256, 0, stream>>>(x, w1as, w1ad, al_s, al_d);
  agg_x_sm<<<nwblk, 256, 0, stream>>>(rowptr, csrc, al_s, al_d, x, p1Hi,
                                      p1Lo);
  gemm_l1_heads<<<dim3((NN + 127) / 128, HEADS), 256, 0, stream>>>(
      p1Hi, p1Lo, w1hHi, w1hLo, p2Hi, p2Lo, b1);

  // ---- Layer 2: h16 = fp16(x1 @ W2); al from h16; softmax-agg -> P1 split -
  const int RB2 = (NN + 127) / 128;     // 157 (128-row panels, MI=4)
  const int G2 = ((RB2 + 7) / 8) * 8 * (WIDTH / 128);  // 640
  gemm_split_db<4><<<G2, 512, 0, stream>>>(
      p2Hi, p2Lo, w2tHi, w2tLo, h16, NN, WIDTH, WIDTH, WIDTH, RB2,
      WIDTH / 128);
  compute_al16<WIDTH, WIDTH><<<nwblk, 256, 0, stream>>>(h16, a2_src, a2_dst,
                                                        al_s, al_d);
  pull_agg_w<<<nwblk, 256, 0, stream>>>(rowptr, csrc, al_s, al_d, h16, b2,
                                        p1Hi, p1Lo);

  // ---- Layer 3: h16 = fp16(x2 @ W3) padded to 128; al; agg -> out ---------
  const int RB3 = (NN + 63) / 64;       // 313 (64-row panels, MI=2)
  const int G3 = ((RB3 + 7) / 8) * 8 * (NCLS_P / 128);  // 320
  gemm_split_db<2><<<G3, 512, 0, stream>>>(
      p1Hi, p1Lo, w3tHi, w3tLo, h16, NN, WIDTH, NCLS, NCLS_P, RB3,
      NCLS_P / 128);
  compute_al16<NCLS, NCLS_P><<<nwblk, 256, 0, stream>>>(h16, a3_src, a3_dst,
                                                        al_s, al_d);
  pull_agg_n<<<(NN + 7) / 8, 256, 0, stream>>>(rowptr, csrc, al_s, al_d, h16,
                                               b3, out);
}

// Round 14
// 388.543 us; speedup vs baseline: 1.1287x; 1.1287x over previous
//
#include <hip/hip_runtime.h>
#include <hip/hip_bf16.h>
#include <hip/hip_fp16.h>

// Problem constants (match reference)
#define NN     20000
#define ERAW   320000
#define ETOT   (ERAW + NN)   // 340000 with self loops
#define F_IN   50
#define HID    64
#define HEADS  8
#define WIDTH  512           // HID*HEADS
#define NCLS   121
#define NCLS_P 128           // padded cols for layer-3 MFMA GEMM + h16 stride

typedef __attribute__((ext_vector_type(8))) __bf16 bf16x8;
typedef __attribute__((ext_vector_type(4))) float floatx4;

// ---------------- fp32 -> bf16 split helpers --------------------------------
__device__ __forceinline__ unsigned short f32_to_bf16_rn(float f) {
  unsigned u = __float_as_uint(f);
  unsigned r = u + 0x7fffu + ((u >> 16) & 1u);
  return (unsigned short)(r >> 16);
}
__device__ __forceinline__ void split_one(float f, unsigned short& h,
                                          unsigned short& l) {
  h = f32_to_bf16_rn(f);
  float fh = __uint_as_float(((unsigned)h) << 16);
  l = f32_to_bf16_rn(f - fh);
}

__device__ __forceinline__ float2 u2f2(unsigned u) {
  __half2 hv = *reinterpret_cast<__half2*>(&u);
  return __half22float2(hv);
}

// async global -> LDS, 16B per lane (dest = wave-uniform base + lane*16)
__device__ __forceinline__ void gll16(const unsigned short* g,
                                      const unsigned short* l) {
  __builtin_amdgcn_global_load_lds(
      (const __attribute__((address_space(1))) unsigned int*)(const void*)g,
      (__attribute__((address_space(3))) unsigned int*)(void*)l, 16, 0, 0);
}

// ---- ONE weight-prep kernel ------------------------------------------------
// R14: W2/W3 are written in MFMA FRAGMENT-MAJOR layout: fragment (kf, g)
// covers cols g*16..+15, k kf*32..+31; ushort offset =
//   (kf*P + g)*512 + ((k>>3)&3)*128 + (m&15)*8 + (k&7),  P = Mp/16.
// A wave's B-fragment load is then ONE contiguous 1KB block (base+lane*16B)
// -> coalesced direct-from-L2 loads in the GEMM (no LDS for B). Pure
// permutation of the same values -> results bit-identical.
#define PW_BLOCKS 449
__global__ __launch_bounds__(256) void prep_weights(
    const float* __restrict__ W1, const float* __restrict__ W2,
    const float* __restrict__ W3, const float* __restrict__ a1s,
    const float* __restrict__ a1d, unsigned short* __restrict__ w1hHi,
    unsigned short* __restrict__ w1hLo, unsigned short* __restrict__ w2tHi,
    unsigned short* __restrict__ w2tLo, unsigned short* __restrict__ w3tHi,
    unsigned short* __restrict__ w3tLo, float* __restrict__ w1as,
    float* __restrict__ w1ad) {
  __shared__ float t[32][33];
  const int b = blockIdx.x;
  if (b < 320) {
    const float* W;
    unsigned short *thi, *tlo;
    int M, Mp, bx, by;
    const int K = WIDTH;
    if (b < 256) {
      W = W2; thi = w2tHi; tlo = w2tLo; M = WIDTH; Mp = WIDTH;
      bx = b & 15; by = b >> 4;
    } else {
      int bb = b - 256;
      W = W3; thi = w3tHi; tlo = w3tLo; M = NCLS; Mp = NCLS_P;
      bx = bb & 15; by = bb >> 4;
    }
    const int P = Mp >> 4;
    int k0 = bx * 32, m0 = by * 32;
    int tx = threadIdx.x & 31, ty = threadIdx.x >> 5;  // 32 x 8
    #pragma unroll
    for (int r = 0; r < 4; ++r) {
      int k = k0 + ty + r * 8, m = m0 + tx;
      float v = 0.f;
      if (k < K && m < M) v = W[(size_t)k * M + m];
      t[ty + r * 8][tx] = v;
    }
    __syncthreads();
    #pragma unroll
    for (int r = 0; r < 4; ++r) {
      int m = m0 + ty + r * 8, k = k0 + tx;
      if (m < Mp && k < K) {
        unsigned short h, l;
        split_one(t[tx][ty + r * 8], h, l);
        size_t off = ((size_t)((k >> 5) * P + (m >> 4))) * 512 +
                     ((k >> 3) & 3) * 128 + (m & 15) * 8 + (k & 7);
        thi[off] = h;
        tlo[off] = l;
      }
    }
  } else if (b < 448) {
    int idx = (b - 320) * 256 + threadIdx.x;
    if (idx < HEADS * HID * HID) {
      int hd = idx >> 12, rem = idx & 4095;
      int col = rem >> 6, k = rem & 63;
      float v = (k < F_IN) ? W1[(size_t)k * WIDTH + hd * HID + col] : 0.f;
      unsigned short h, l;
      split_one(v, h, l);
      w1hHi[idx] = h;
      w1hLo[idx] = l;
    }
  } else {
    for (int idx = threadIdx.x; idx < 2 * F_IN * HEADS; idx += 256) {
      int which = idx >= F_IN * HEADS;
      int r = which ? idx - F_IN * HEADS : idx;
      int k = r >> 3, h = r & 7;
      const float* a = which ? a1d : a1s;
      float s = 0.f;
      for (int c = 0; c < HID; ++c)
        s += W1[(size_t)k * WIDTH + h * HID + c] * a[h * HID + c];
      (which ? w1ad : w1as)[r] = s;
    }
  }
}

// ---- split-bf16 MFMA GEMM, (MI*32)x128 tile, BK=64, 8 waves ---------------
// R14: A (hi+lo) staged in LDS exactly as R12 (coalesced gll16, chunk-XOR
// swizzle, counted vmcnt). B (hi+lo) is NOT staged: fragment-major-packed
// by prep_weights, so each B-fragment is a contiguous 1KB coalesced load
// straight from L2 (B panel is 256KB/XCD-resident). LDS halves ->
// 2 blocks/CU = 4 waves/SIMD (MI=4). Fragment values and MFMA order
// unchanged -> bit-identical.
template <int MI>
__global__ __launch_bounds__(512, 4) void gemm_split_db(
    const unsigned short* __restrict__ Ahi, const unsigned short* __restrict__ Alo,
    const unsigned short* __restrict__ Bthi, const unsigned short* __restrict__ Btlo,
    __half* __restrict__ C16, int N, int K, int M, int Mp, int RB, int CB) {
  constexpr int ABUF = MI * 2048;          // ushorts of Ahi region (rows*64)
  constexpr int BUF = MI * 4096;           // per buffer: Ahi+Alo
  constexpr int NGW = MI;                  // gll16 per wave per K-step
  __shared__ unsigned short lds[2 * BUF];

  const int f = blockIdx.x;
  const int xcd = f & 7;
  const int g = f >> 3;
  const int cb = g % CB;
  const int rb = (g / CB) * 8 + xcd;
  if (rb >= RB) return;
  const int r0 = rb * (MI * 32), c0 = cb * 128;

  const int tid = threadIdx.x;
  const int wave = tid >> 6, lane = tid & 63;
  const int wr = wave >> 2, wc = wave & 3;  // 2x4 waves, (MI*16)x32 out each
  const int lkg = lane >> 4, lmn = lane & 15;
  const int P = Mp >> 4;

  // --- A staging: 2 arrays (hi,lo) x MI*4 rowgroups = MI*8 gll16 total;
  //     wave w issues NGW=MI of them.
  const int row8 = lane >> 3, cslot = lane & 7;
  const unsigned short* gsrc[NGW];
  int ldsoff[NGW];
  #pragma unroll
  for (int i = 0; i < NGW; ++i) {
    int q = wave * NGW + i;
    int a = (q < MI * 4) ? 0 : 1;          // 0 = Ahi, 1 = Alo
    int rg = (a == 0) ? q : q - MI * 4;
    int r = rg * 8 + row8;
    int c = cslot ^ (r & 7);              // pre-swizzled chunk (involution)
    const unsigned short* base = a ? Alo : Ahi;
    int ra = r0 + r;
    if (ra > N - 1) ra = N - 1;
    gsrc[i] = base + (size_t)ra * K + c * 8;
    ldsoff[i] = a * ABUF + rg * 512;      // wave-uniform dest base
  }

  int rowA[MI], m7A[MI];
  #pragma unroll
  for (int mi = 0; mi < MI; ++mi) {
    int m = wr * (MI * 16) + mi * 16 + lmn;
    rowA[mi] = m * 64;  m7A[mi] = m & 7;
  }
  const int g0 = (c0 >> 4) + wc * 2;      // this wave's B col-groups

  floatx4 acc[MI][2] = {};

  // prologue: tile 0 A -> buffer 0
  #pragma unroll
  for (int i = 0; i < NGW; ++i) gll16(gsrc[i], lds + ldsoff[i]);

  const int nk = K >> 6;  // K-steps of 64
  for (int t = 0; t < nk; ++t) {
    if (t + 1 < nk) {
      const unsigned short* dst = lds + ((t + 1) & 1) * BUF;
      #pragma unroll
      for (int i = 0; i < NGW; ++i)
        gll16(gsrc[i] + (t + 1) * 64, dst + ldsoff[i]);
      if constexpr (MI == 4) {
        asm volatile("s_waitcnt vmcnt(4)" ::: "memory");  // tile t landed
      } else {
        asm volatile("s_waitcnt vmcnt(2)" ::: "memory");
      }
    } else {
      asm volatile("s_waitcnt vmcnt(0)" ::: "memory");
    }
    __builtin_amdgcn_sched_barrier(0);
    __builtin_amdgcn_s_barrier();          // all waves' tile-t loads visible
    __builtin_amdgcn_sched_barrier(0);

    const unsigned short* Lb = lds + (t & 1) * BUF;
    #pragma unroll
    for (int ksub = 0; ksub < 2; ++ksub) {  // ascending K within tile
      bf16x8 fAhi[MI], fAlo[MI], fBhi[2], fBlo[2];
      #pragma unroll
      for (int mi = 0; mi < MI; ++mi) {
        int s = rowA[mi] + (((ksub << 2) | lkg) ^ m7A[mi]) * 8;
        fAhi[mi] = *(const bf16x8*)(Lb + s);
        fAlo[mi] = *(const bf16x8*)(Lb + s + ABUF);
      }
      const size_t fbase = ((size_t)(t * 2 + ksub) * P + g0) * 512 + lane * 8;
      #pragma unroll
      for (int ni = 0; ni < 2; ++ni) {
        fBhi[ni] = *(const bf16x8*)(Bthi + fbase + ni * 512);  // 1KB coalesced
        fBlo[ni] = *(const bf16x8*)(Btlo + fbase + ni * 512);
      }
      // same 3-term split, same per-acc order as before -> bit-identical
      #pragma unroll
      for (int mi = 0; mi < MI; ++mi)
        #pragma unroll
        for (int ni = 0; ni < 2; ++ni) {
          acc[mi][ni] = __builtin_amdgcn_mfma_f32_16x16x32_bf16(
              fAhi[mi], fBhi[ni], acc[mi][ni], 0, 0, 0);
          acc[mi][ni] = __builtin_amdgcn_mfma_f32_16x16x32_bf16(
              fAhi[mi], fBlo[ni], acc[mi][ni], 0, 0, 0);
          acc[mi][ni] = __builtin_amdgcn_mfma_f32_16x16x32_bf16(
              fAlo[mi], fBhi[ni], acc[mi][ni], 0, 0, 0);
        }
    }

    __builtin_amdgcn_sched_barrier(0);
    asm volatile("s_waitcnt lgkmcnt(0)" ::: "memory");
    __builtin_amdgcn_s_barrier();          // WAR: next issue overwrites buf
    __builtin_amdgcn_sched_barrier(0);
  }

  #pragma unroll
  for (int mi = 0; mi < MI; ++mi) {
    #pragma unroll
    for (int r = 0; r < 4; ++r) {
      int grow = r0 + wr * (MI * 16) + mi * 16 + lkg * 4 + r;
      if (grow >= N) continue;
      #pragma unroll
      for (int ni = 0; ni < 2; ++ni) {
        int gcol = c0 + wc * 32 + ni * 16 + lmn;
        float v = (gcol < M) ? acc[mi][ni][r] : 0.f;
        C16[(size_t)grow * Mp + gcol] = __float2half(v);
      }
    }
  }
}

// ---- batched per-head L1 GEMM: C[n,hd*64+c] = elu(A[n,hd*64+:64]@W1h + b1) -
__global__ __launch_bounds__(256) void gemm_l1_heads(
    const unsigned short* __restrict__ Ahi, const unsigned short* __restrict__ Alo,
    const unsigned short* __restrict__ Bthi, const unsigned short* __restrict__ Btlo,
    unsigned short* __restrict__ outHi, unsigned short* __restrict__ outLo,
    const float* __restrict__ bias) {
  __shared__ unsigned short sAhi[8192], sAlo[8192], sBhi[4096], sBlo[4096];
  const int tid = threadIdx.x;
  const int wave = tid >> 6, lane = tid & 63;
  const int r0 = blockIdx.x * 128;
  const int hd = blockIdx.y;
  const int lkg = lane >> 4, lmn = lane & 15;

  #pragma unroll
  for (int t = 0; t < 4; ++t) {
    int cid = tid + t * 256;
    int row = cid >> 3, c = cid & 7;
    int gr = r0 + row; if (gr > NN - 1) gr = NN - 1;
    const size_t goff = (size_t)gr * WIDTH + hd * HID + c * 8;
    int loff = (((c >> 2) * 4 + (c & 3)) * 128 + row) * 8;
    *(uint4*)(sAhi + loff) = *(const uint4*)(Ahi + goff);
    *(uint4*)(sAlo + loff) = *(const uint4*)(Alo + goff);
  }
  #pragma unroll
  for (int t = 0; t < 2; ++t) {
    int cid = tid + t * 256;
    int col = cid >> 3, c = cid & 7;
    const size_t goff = (size_t)(hd * HID + col) * HID + c * 8;
    int loff = (((c >> 2) * 4 + (c & 3)) * 64 + col) * 8;
    *(uint4*)(sBhi + loff) = *(const uint4*)(Bthi + goff);
    *(uint4*)(sBlo + loff) = *(const uint4*)(Btlo + goff);
  }
  __syncthreads();

  floatx4 acc[2][4] = {};
  #pragma unroll
  for (int ks = 0; ks < 2; ++ks) {
    bf16x8 fAhi[2], fAlo[2], fBhi[4], fBlo[4];
    #pragma unroll
    for (int mi = 0; mi < 2; ++mi) {
      int m = wave * 32 + mi * 16 + lmn;
      int off = ((ks * 4 + lkg) * 128 + m) * 8;
      fAhi[mi] = *(const bf16x8*)(sAhi + off);
      fAlo[mi] = *(const bf16x8*)(sAlo + off);
    }
    #pragma unroll
    for (int ni = 0; ni < 4; ++ni) {
      int n = ni * 16 + lmn;
      int off = ((ks * 4 + lkg) * 64 + n) * 8;
      fBhi[ni] = *(const bf16x8*)(sBhi + off);
      fBlo[ni] = *(const bf16x8*)(sBlo + off);
    }
    #pragma unroll
    for (int mi = 0; mi < 2; ++mi)
      #pragma unroll
      for (int ni = 0; ni < 4; ++ni) {
        acc[mi][ni] = __builtin_amdgcn_mfma_f32_16x16x32_bf16(
            fAhi[mi], fBhi[ni], acc[mi][ni], 0, 0, 0);
        acc[mi][ni] = __builtin_amdgcn_mfma_f32_16x16x32_bf16(
            fAhi[mi], fBlo[ni], acc[mi][ni], 0, 0, 0);
        acc[mi][ni] = __builtin_amdgcn_mfma_f32_16x16x32_bf16(
            fAlo[mi], fBhi[ni], acc[mi][ni], 0, 0, 0);
      }
  }

  #pragma unroll
  for (int mi = 0; mi < 2; ++mi) {
    #pragma unroll
    for (int r = 0; r < 4; ++r) {
      int grow = r0 + wave * 32 + mi * 16 + (lane >> 4) * 4 + r;
      if (grow >= NN) continue;
      #pragma unroll
      for (int ni = 0; ni < 4; ++ni) {
        int gcol = hd * HID + ni * 16 + lmn;
        float v = acc[mi][ni][r] + bias[gcol];
        v = (v > 0.f) ? v : (__expf(v) - 1.0f);
        unsigned short hh, ll;
        split_one(v, hh, ll);
        outHi[(size_t)grow * WIDTH + gcol] = hh;
        outLo[(size_t)grow * WIDTH + gcol] = ll;
      }
    }
  }
}

// al1[n,h] = sum_k x[n,k] * w1a[k,h]   (one wave per node)
__global__ __launch_bounds__(256) void al1_kernel(
    const float* __restrict__ x, const float* __restrict__ w1as,
    const float* __restrict__ w1ad, float* __restrict__ al_s,
    float* __restrict__ al_d) {
  int n = (blockIdx.x * blockDim.x + threadIdx.x) >> 6;
  int lane = threadIdx.x & 63;
  if (n >= NN) return;
  float xv = (lane < F_IN) ? x[(size_t)n * F_IN + lane] : 0.f;
  float ws[HEADS], wd[HEADS];
  #pragma unroll
  for (int h = 0; h < HEADS; ++h) {
    ws[h] = (lane < F_IN) ? w1as[lane * HEADS + h] : 0.f;
    wd[h] = (lane < F_IN) ? w1ad[lane * HEADS + h] : 0.f;
  }
  #pragma unroll
  for (int h = 0; h < HEADS; ++h) {
    float ss = xv * ws[h], sd = xv * wd[h];
    #pragma unroll
    for (int o = 32; o; o >>= 1) {
      ss += __shfl_xor(ss, o);
      sd += __shfl_xor(sd, o);
    }
    if (lane == 0) {
      al_s[n * HEADS + h] = ss;
      al_d[n * HEADS + h] = sd;
    }
  }
}

// ---------------- per-node attention logits from fp16 h (H=1 layers) -------
template <int C, int CS>
__global__ __launch_bounds__(256) void compute_al16(
    const __half* __restrict__ h16, const float* __restrict__ a_src,
    const float* __restrict__ a_dst, float* __restrict__ al_s,
    float* __restrict__ al_d) {
  int n = (blockIdx.x * blockDim.x + threadIdx.x) >> 6;
  int lane = threadIdx.x & 63;
  if (n >= NN) return;
  const __half* hr = h16 + (size_t)n * CS;
  float ss = 0.f, sd = 0.f;
  if (C % 512 == 0) {
    uint4 raw = *(const uint4*)(hr + lane * 8);
    float f[8];
    float2 t;
    t = u2f2(raw.x); f[0] = t.x; f[1] = t.y;
    t = u2f2(raw.y); f[2] = t.x; f[3] = t.y;
    t = u2f2(raw.z); f[4] = t.x; f[5] = t.y;
    t = u2f2(raw.w); f[6] = t.x; f[7] = t.y;
    #pragma unroll
    for (int j = 0; j < 8; ++j) {
      int c = lane * 8 + j;
      ss += f[j] * a_src[c];
      sd += f[j] * a_dst[c];
    }
  } else {
    for (int c = lane; c < C; c += 64) {
      float v = __half2float(hr[c]);
      ss += v * a_src[c];
      sd += v * a_dst[c];
    }
  }
  #pragma unroll
  for (int o = 32; o; o >>= 1) {
    ss += __shfl_xor(ss, o);
    sd += __shfl_xor(sd, o);
  }
  if (lane == 0) {
    al_s[n] = ss;
    al_d[n] = sd;
  }
}

// ---------------- CSR build (once; shared by all layers) --------------------
__global__ __launch_bounds__(256) void count_deg(
    const int* __restrict__ edst, int* __restrict__ deg) {
  int e = blockIdx.x * blockDim.x + threadIdx.x;
  if (e >= ETOT) return;
  int d = (e < ERAW) ? edst[e] : (e - ERAW);
  atomicAdd(&deg[d], 1);
}

__global__ __launch_bounds__(1024) void scan_deg(
    const int* __restrict__ deg, int* __restrict__ rowptr) {
  __shared__ int part[1024];
  const int t = threadIdx.x;
  const int CHUNK = (NN + 1023) / 1024;
  int lo = t * CHUNK, hi = min(lo + CHUNK, NN);
  int s = 0;
  for (int i = lo; i < hi; ++i) s += deg[i];
  part[t] = s;
  __syncthreads();
  for (int off = 1; off < 1024; off <<= 1) {
    int v = (t >= off) ? part[t - off] : 0;
    __syncthreads();
    part[t] += v;
    __syncthreads();
  }
  int base = (t == 0) ? 0 : part[t - 1];
  for (int i = lo; i < hi; ++i) {
    rowptr[i] = base;
    base += deg[i];
  }
  if (t == 1023) rowptr[NN] = part[1023];
}

__global__ __launch_bounds__(256) void scatter_csr(
    const int* __restrict__ esrc, const int* __restrict__ edst,
    const int* __restrict__ rowptr, int* __restrict__ cnt,
    int* __restrict__ csrc) {
  int e = blockIdx.x * blockDim.x + threadIdx.x;
  if (e >= ETOT) return;
  int s, d;
  if (e < ERAW) { s = esrc[e]; d = edst[e]; }
  else          { s = e - ERAW; d = e - ERAW; }
  int pos = rowptr[d] + atomicAdd(&cnt[d], 1);
  csrc[pos] = s;
}

// ---- layer-1 fused SINGLE-PASS softmax+aggregate (self-loop-logit shift) --
// (R10 form: unroll-8 chunks + scalar tail; ascending-p order)
__global__ __launch_bounds__(256) void agg_x_sm(
    const int* __restrict__ rowptr, const int* __restrict__ csrc,
    const float* __restrict__ al_s, const float* __restrict__ al_d,
    const float* __restrict__ x, unsigned short* __restrict__ outHi,
    unsigned short* __restrict__ outLo) {
  const int w = threadIdx.x >> 6, lane = threadIdx.x & 63;
  const int d = blockIdx.x * 4 + w;
  if (d >= NN) return;
  const int r0 = rowptr[d], r1 = rowptr[d + 1];
  const int mh = lane & 7;
  const float ald_my = al_d[d * HEADS + mh];
  float m_my = al_s[d * HEADS + mh] + ald_my;
  m_my = (m_my > 0.f) ? m_my : 0.2f * m_my;

  float z_my = 0.f;
  float acc[HEADS];
  #pragma unroll
  for (int hh = 0; hh < HEADS; ++hh) acc[hh] = 0.f;

  int p = r0;
  for (; p + 8 <= r1; p += 8) {
    int s[8];
    #pragma unroll
    for (int j = 0; j < 8; ++j) s[j] = csrc[p + j];
    float xv[8];
    #pragma unroll
    for (int j = 0; j < 8; ++j)
      xv[j] = (lane < F_IN) ? x[(size_t)s[j] * F_IN + lane] : 0.f;
    float av[8];
    #pragma unroll
    for (int j = 0; j < 8; ++j) av[j] = al_s[s[j] * HEADS + mh];
    #pragma unroll
    for (int j = 0; j < 8; ++j) {          // strictly ascending p
      float v = av[j] + ald_my;
      v = (v > 0.f) ? v : 0.2f * v;
      float a = __expf(v - m_my);
      z_my += a;
      #pragma unroll
      for (int hh = 0; hh < HEADS; ++hh) acc[hh] += __shfl(a, hh, 8) * xv[j];
    }
  }
  for (; p < r1; ++p) {
    int s = csrc[p];
    float v = al_s[s * HEADS + mh] + ald_my;
    v = (v > 0.f) ? v : 0.2f * v;
    float a = __expf(v - m_my);
    z_my += a;
    float xv = (lane < F_IN) ? x[(size_t)s * F_IN + lane] : 0.f;
    #pragma unroll
    for (int hh = 0; hh < HEADS; ++hh) acc[hh] += __shfl(a, hh, 8) * xv;
  }

  #pragma unroll
  for (int hh = 0; hh < HEADS; ++hh) {
    float zh = __shfl(z_my, hh, 8);
    float v = (lane < F_IN) ? acc[hh] / (zh + 1e-16f) : 0.f;
    unsigned short h2, l2;
    split_one(v, h2, l2);
    outHi[(size_t)d * WIDTH + hh * HID + lane] = h2;
    outLo[(size_t)d * WIDTH + hh * HID + lane] = l2;
  }
}

// ---- L2 fused SINGLE-PASS softmax + pull aggregation (512 cols) -----------
// (R10 form: unroll-8 chunks + scalar tail, early gathers; bandwidth-bound)
__global__ __launch_bounds__(256) void pull_agg_w(
    const int* __restrict__ rowptr, const int* __restrict__ csrc,
    const float* __restrict__ al_s, const float* __restrict__ al_d,
    const __half* __restrict__ h16, const float* __restrict__ bias,
    unsigned short* __restrict__ outHi, unsigned short* __restrict__ outLo) {
  const int w = threadIdx.x >> 6;
  const int lane = threadIdx.x & 63;
  const int d = blockIdx.x * 4 + w;
  if (d >= NN) return;
  const int r0 = rowptr[d], r1 = rowptr[d + 1];
  const float ald = al_d[d];
  float m = al_s[d] + ald;                 // self-loop logit as softmax shift
  m = (m > 0.f) ? m : 0.2f * m;

  const int base = lane * 8;
  const __half* hb = h16 + base;
  float acc[8];
  #pragma unroll
  for (int j = 0; j < 8; ++j) acc[j] = 0.f;
  float z = 0.f;

  int p = r0;
  for (; p + 8 <= r1; p += 8) {
    int s[8];
    #pragma unroll
    for (int j = 0; j < 8; ++j) s[j] = csrc[p + j];
    uint4 raw8[8];
    #pragma unroll
    for (int j = 0; j < 8; ++j)
      raw8[j] = *(const uint4*)(hb + (size_t)s[j] * WIDTH);
    float av[8];
    #pragma unroll
    for (int j = 0; j < 8; ++j) av[j] = al_s[s[j]];
    #pragma unroll
    for (int j = 0; j < 8; ++j) {          // strictly ascending p
      float v = av[j] + ald;
      v = (v > 0.f) ? v : 0.2f * v;
      float a = __expf(v - m);
      z += a;
      float2 f0 = u2f2(raw8[j].x), f1 = u2f2(raw8[j].y);
      float2 f2 = u2f2(raw8[j].z), f3 = u2f2(raw8[j].w);
      acc[0] += f0.x * a; acc[1] += f0.y * a;
      acc[2] += f1.x * a; acc[3] += f1.y * a;
      acc[4] += f2.x * a; acc[5] += f2.y * a;
      acc[6] += f3.x * a; acc[7] += f3.y * a;
    }
  }
  for (; p < r1; ++p) {
    int s = csrc[p];
    float v = al_s[s] + ald;
    v = (v > 0.f) ? v : 0.2f * v;
    float a = __expf(v - m);
    z += a;
    uint4 raw = *(const uint4*)(hb + (size_t)s * WIDTH);
    float2 f0 = u2f2(raw.x), f1 = u2f2(raw.y);
    float2 f2 = u2f2(raw.z), f3 = u2f2(raw.w);
    acc[0] += f0.x * a; acc[1] += f0.y * a;
    acc[2] += f1.x * a; acc[3] += f1.y * a;
    acc[4] += f2.x * a; acc[5] += f2.y * a;
    acc[6] += f3.x * a; acc[7] += f3.y * a;
  }
  const float iz = 1.0f / (z + 1e-16f);

  #pragma unroll
  for (int j = 0; j < 8; ++j) {
    float v = acc[j] * iz + bias[base + j];
    v = (v > 0.f) ? v : (__expf(v) - 1.0f);   // ELU
    unsigned short hh, ll;
    split_one(v, hh, ll);
    outHi[(size_t)d * WIDTH + base + j] = hh;
    outLo[(size_t)d * WIDTH + base + j] = ll;
  }
}

// ---- L3 pull aggregation: TWO destinations per wave (half-wave each) ------
__global__ __launch_bounds__(256) void pull_agg_n(
    const int* __restrict__ rowptr, const int* __restrict__ csrc,
    const float* __restrict__ al_s, const float* __restrict__ al_d,
    const __half* __restrict__ h16, const float* __restrict__ bias,
    float* __restrict__ out) {
  const int w = threadIdx.x >> 6, lane = threadIdx.x & 63;
  const int half = lane >> 5, li = lane & 31;
  const int d = blockIdx.x * 8 + w * 2 + half;
  if (d >= NN) return;
  const int r0 = rowptr[d], r1 = rowptr[d + 1];
  const float ald = al_d[d];
  float m = al_s[d] + ald;
  m = (m > 0.f) ? m : 0.2f * m;

  const int base = li * 4;                // 32 lanes x 4 cols = 128
  const __half* hb = h16 + base;
  float acc[4] = {0.f, 0.f, 0.f, 0.f};
  float z = 0.f;

  for (int p = r0; p < r1; p += 8) {
    int s[8];
    #pragma unroll
    for (int j = 0; j < 8; ++j) {
      int pj = p + j; if (pj > r1 - 1) pj = r1 - 1;
      s[j] = csrc[pj];
    }
    uint2 raw[8];                          // 8B = 4 fp16
    #pragma unroll
    for (int j = 0; j < 8; ++j)
      raw[j] = *(const uint2*)(hb + (size_t)s[j] * NCLS_P);
    float av[8];
    #pragma unroll
    for (int j = 0; j < 8; ++j) av[j] = al_s[s[j]];
    #pragma unroll
    for (int j = 0; j < 8; ++j) {          // strictly ascending p
      float v = av[j] + ald;
      v = (v > 0.f) ? v : 0.2f * v;
      float a = __expf(v - m);
      if (p + j >= r1) a = 0.f;            // masked tail: exact +0.0f
      z += a;
      float2 f0 = u2f2(raw[j].x), f1 = u2f2(raw[j].y);
      acc[0] += f0.x * a; acc[1] += f0.y * a;
      acc[2] += f1.x * a; acc[3] += f1.y * a;
    }
  }
  const float iz = 1.0f / (z + 1e-16f);

  #pragma unroll
  for (int j = 0; j < 4; ++j) {
    int col = base + j;
    if (col < NCLS)
      out[(size_t)d * NCLS + col] = acc[j] * iz + bias[col];
  }
}

extern "C" void kernel_launch(void* const* d_in, const int* in_sizes, int n_in,
                              void* d_out, int out_size, void* d_ws,
                              size_t ws_size, hipStream_t stream) {
  const float* x      = (const float*)d_in[0];
  const int*   ei     = (const int*)d_in[1];
  const float* W1     = (const float*)d_in[2];
  const float* a1_src = (const float*)d_in[3];
  const float* a1_dst = (const float*)d_in[4];
  const float* b1     = (const float*)d_in[5];
  const float* W2     = (const float*)d_in[6];
  const float* a2_src = (const float*)d_in[7];
  const float* a2_dst = (const float*)d_in[8];
  const float* b2     = (const float*)d_in[9];
  const float* W3     = (const float*)d_in[10];
  const float* a3_src = (const float*)d_in[11];
  const float* a3_dst = (const float*)d_in[12];
  const float* b3     = (const float*)d_in[13];
  float* out = (float*)d_out;

  const int* esrc = ei;
  const int* edst = ei + ERAW;

  // Workspace carve-up
  unsigned short* p1Hi  = (unsigned short*)d_ws;          // NN*WIDTH
  unsigned short* p1Lo  = p1Hi + (size_t)NN * WIDTH;
  unsigned short* p2Hi  = p1Lo + (size_t)NN * WIDTH;
  unsigned short* p2Lo  = p2Hi + (size_t)NN * WIDTH;
  __half*        h16    = (__half*)(p2Lo + (size_t)NN * WIDTH);  // NN*WIDTH
  unsigned short* w1hHi = (unsigned short*)(h16 + (size_t)NN * WIDTH);
  unsigned short* w1hLo = w1hHi + (size_t)HEADS * HID * HID;
  unsigned short* w2tHi = w1hLo + (size_t)HEADS * HID * HID;  // 512*512
  unsigned short* w2tLo = w2tHi + (size_t)WIDTH * WIDTH;
  unsigned short* w3tHi = w2tLo + (size_t)WIDTH * WIDTH;  // 128*512
  unsigned short* w3tLo = w3tHi + (size_t)NCLS_P * WIDTH;
  float* al_s   = (float*)(w3tLo + (size_t)NCLS_P * WIDTH);  // NN*HEADS
  float* al_d   = al_s + (size_t)NN * HEADS;
  float* w1as   = al_d + (size_t)NN * HEADS;              // 50*8
  float* w1ad   = w1as + F_IN * HEADS;
  int* deg      = (int*)(w1ad + F_IN * HEADS);            // NN
  int* cnt      = deg + NN;                               // NN  (adjacent!)
  int* rowptr   = cnt + NN;                               // NN+1 (+3 pad)
  int* csrc     = rowptr + NN + 4;                        // ETOT

  // ---- build CSR by destination (once): ONE memset covers deg+cnt ----
  hipMemsetAsync(deg, 0, (size_t)(2 * NN) * sizeof(int), stream);
  const int eblk = (ETOT + 255) / 256;
  count_deg<<<eblk, 256, 0, stream>>>(edst, deg);
  scan_deg<<<1, 1024, 0, stream>>>(deg, rowptr);
  scatter_csr<<<eblk, 256, 0, stream>>>(esrc, edst, rowptr, cnt, csrc);

  // ---- ALL weight prep in one dispatch ----
  prep_weights<<<PW_BLOCKS, 256, 0, stream>>>(
      W1, W2, W3, a1_src, a1_dst, w1hHi, w1hLo, w2tHi, w2tLo, w3tHi, w3tLo,
      w1as, w1ad);

  const int nwblk = (NN + 3) / 4;

  // ---- Layer 1 (aggregate-x-first; single-pass softmax+agg; head GEMM) ----
  al1_kernel<<<nwblk, 256, 0, stream>>>(x, w1as, w1ad, al_s, al_d);
  agg_x_sm<<<nwblk, 256, 0, stream>>>(rowptr, csrc, al_s, al_d, x, p1Hi,
                                      p1Lo);
  gemm_l1_heads<<<dim3((NN + 127) / 128, HEADS), 256, 0, stream>>>(
      p1Hi, p1Lo, w1hHi, w1hLo, p2Hi, p2Lo, b1);

  // ---- Layer 2: h16 = fp16(x1 @ W2); al from h16; softmax-agg -> P1 split -
  const int RB2 = (NN + 127) / 128;     // 157 (128-row panels, MI=4)
  const int G2 = ((RB2 + 7) / 8) * 8 * (WIDTH / 128);  // 640
  gemm_split_db<4><<<G2, 512, 0, stream>>>(
      p2Hi, p2Lo, w2tHi, w2tLo, h16, NN, WIDTH, WIDTH, WIDTH, RB2,
      WIDTH / 128);
  compute_al16<WIDTH, WIDTH><<<nwblk, 256, 0, stream>>>(h16, a2_src, a2_dst,
                                                        al_s, al_d);
  pull_agg_w<<<nwblk, 256, 0, stream>>>(rowptr, csrc, al_s, al_d, h16, b2,
                                        p1Hi, p1Lo);

  // ---- Layer 3: h16 = fp16(x2 @ W3) padded to 128; al; agg -> out ---------
  const int RB3 = (NN + 63) / 64;       // 313 (64-row panels, MI=2)
  const int G3 = ((RB3 + 7) / 8) * 8 * (NCLS_P / 128);  // 320
  gemm_split_db<2><<<G3, 512, 0, stream>>>(
      p1Hi, p1Lo, w3tHi, w3tLo, h16, NN, WIDTH, NCLS, NCLS_P, RB3,
      NCLS_P / 128);
  compute_al16<NCLS, NCLS_P><<<nwblk, 256, 0, stream>>>(h16, a3_src, a3_dst,
                                                        al_s, al_d);
  pull_agg_n<<<(NN + 7) / 8, 256, 0, stream>>>(rowptr, csrc, al_s, al_d, h16,
                                               b3, out);
}